// Round 1
// baseline (808.238 us; speedup 1.0000x reference)
//
#include <hip/hip_runtime.h>
#include <stdint.h>

// CTC forward loss, B=512, T=1024, C=256, L=64, S=129, blank=C-1.
// One wave (64 lanes) per batch element. Lane i holds alpha[2i], alpha[2i+1];
// lane 63 additionally alpha[128]. Cross-state deps via one __shfl_up.
//
// R2: coalesced row staging via global_load_lds (1KB/row) into a 32-row LDS
// ring, manual s_waitcnt vmcnt(31) pipelining, per-lane label gather from LDS.
//
// R3 change: the R2 gathers were compiler-visible ds_reads aliasing the LDS
// DMA destination, so the waitcnt pass inserted s_waitcnt vmcnt(0) before
// every gather -> full 32-deep pipeline drain every step -> one loaded HBM
// latency (~1870 cyc) per step (799us, 672 GB/s = 8% of HBM). Fix: do the
// gathers with volatile inline-asm ds_read_b32 on raw AS(3) offsets so the
// waitcnt pass cannot see the aliasing and inserts nothing; row residency is
// guaranteed by the manual vmcnt(31) invariant alone. Consumption is guarded
// by a counted s_waitcnt lgkmcnt(2) + sched_barrier(0) at update() entry
// (the 2 newest DS ops there are always the just-issued prefetch pair for a
// later step; the pair being consumed is older and thus retired).

#define EPS 1e-7f
#define NEG -1e30f

constexpr int Bb = 512;
constexpr int Tt = 1024;
constexpr int Cc = 256;
constexpr int Ll = 64;
constexpr int BLANK = Cc - 1;
constexpr int D = 32; // LDS ring depth in rows (32 x 1KB = 32 KiB)

// Wait until at most 31 vector-memory ops outstanding. Inline asm with
// "memory" clobber so the compiler neither reorders LDS ops across it nor
// drops the ordering vs the global_load_lds builtins.
#define WAITVM31() asm volatile("s_waitcnt vmcnt(31)" ::: "memory")

// Guard before consuming asm-gathered values: all DS ops except the 2 newest
// (the just-issued prefetch pair) have retired. sched_barrier(0) stops the
// scheduler hoisting the dependent VALU above the wait (rule: inline-asm
// ds_read + waitcnt needs a following sched_barrier).
#define WAITLGKM2()                                        \
    do {                                                   \
        asm volatile("s_waitcnt lgkmcnt(2)" ::: "memory"); \
        __builtin_amdgcn_sched_barrier(0);                 \
    } while (0)

#define WAITLGKM0()                                        \
    do {                                                   \
        asm volatile("s_waitcnt lgkmcnt(0)" ::: "memory"); \
        __builtin_amdgcn_sched_barrier(0);                 \
    } while (0)

__device__ __forceinline__ void dma_row(const float* __restrict__ g,
                                        float* l) {
    // 64 lanes x 16B -> LDS base + lane*16 (wave-uniform base, contiguous).
    __builtin_amdgcn_global_load_lds(
        (const __attribute__((address_space(1))) void*)g,
        (__attribute__((address_space(3))) void*)l, 16, 0, 0);
}

// Gather one float from LDS via inline asm: invisible to the waitcnt pass,
// so it does NOT trigger a conservative vmcnt(0) drain of the DMA queue.
__device__ __forceinline__ float lds_gather(const float* p) {
    float v;
    const uint32_t off = (uint32_t)(uintptr_t)(
        const __attribute__((address_space(3))) void*)p;
    asm volatile("ds_read_b32 %0, %1" : "=v"(v) : "v"(off));
    return v;
}

__global__ __launch_bounds__(64) void ctc_fwd_kernel(
    const int* __restrict__ y_true,   // [B, L] int32
    const float* __restrict__ y_pred, // [B, T, C] float32 probabilities
    float* __restrict__ out)          // [B] float32
{
    const int b = blockIdx.x;
    const int lane = threadIdx.x; // 0..63

    const float* __restrict__ row0 = y_pred + (size_t)b * Tt * Cc;

    __shared__ float ring[D * Cc]; // 32 KiB

    // Label for odd state 2*lane+1. Consume it (shfl) BEFORE issuing DMAs so
    // the compiler's vmcnt wait for this load doesn't drain the DMA queue.
    const int lab = y_true[b * Ll + lane];
    const int lab_prev = __shfl_up(lab, 1);
    const bool allow = (lane == 0) ? true : (lab != lab_prev);

    // ---- prologue: issue rows 0..D-1 into slots 0..D-1 ----
    for (int t0 = 0; t0 < D; ++t0)
        dma_row(row0 + t0 * Cc + lane * 4, &ring[t0 * Cc]);

    WAITVM31(); // row 0 resident (31 younger loads may be outstanding)
    const float pl0 = lds_gather(&ring[lab]);
    const float pb0 = lds_gather(&ring[BLANK]);
    WAITLGKM0(); // immediate use below
    float ae = (lane == 0) ? __logf(pb0 + EPS) : NEG; // alpha[2i]
    float ao = (lane == 0) ? __logf(pl0 + EPS) : NEG; // alpha[2i+1]
    float a128 = NEG;                                 // alpha[128] (lane 63)

    dma_row(row0 + D * Cc + lane * 4, &ring[0]); // row D -> slot 0
    WAITVM31();                                  // row 1 resident
    float glA = lds_gather(&ring[1 * Cc + lab]);
    float gbA = lds_gather(&ring[1 * Cc + BLANK]);
    dma_row(row0 + (D + 1) * Cc + lane * 4, &ring[1 * Cc]); // row D+1
    WAITVM31();                                             // row 2 resident
    float glB = lds_gather(&ring[2 * Cc + lab]);
    float gbB = lds_gather(&ring[2 * Cc + BLANK]);

    auto update = [&](float gl, float gb) {
        // gl/gb were gathered >= one full update earlier; the 2 newest DS
        // ops are the prefetch pair for a later step -> this wait is free.
        WAITLGKM2();
        const float lpl = __logf(gl + EPS);
        const float lpb = __logf(gb + EPS);
        float ao_up = __shfl_up(ao, 1);
        if (lane == 0) ao_up = NEG;

        // even state s=2i: from alpha[2i], alpha[2i-1]; emits blank
        const float m2 = fmaxf(ae, ao_up);
        const float ne =
            m2 + __logf(__expf(ae - m2) + __expf(ao_up - m2)) + lpb;

        // odd state s=2i+1: from alpha[2i+1], alpha[2i], (allow) alpha[2i-1]
        const float a3 = allow ? ao_up : NEG;
        const float m3 = fmaxf(fmaxf(ao, ae), a3);
        const float no =
            m3 +
            __logf(__expf(ao - m3) + __expf(ae - m3) + __expf(a3 - m3)) +
            lpl;

        // state 128 (lane 63): from alpha[128], alpha[127]; emits blank
        const float m1 = fmaxf(a128, ao);
        const float n128 =
            m1 + __logf(__expf(a128 - m1) + __expf(ao - m1)) + lpb;

        ae = ne;
        ao = no;
        a128 = n128;
    };

    // steps t = 1 .. 1022 in pairs; invariant at pair top: last issued
    // row (virtual) = t + D. Each body: compute step, issue row t+1+D into
    // slot (t+1)&31 (gathered one iteration ago -> safe), wait vmcnt(31)
    // (=> row t+2 resident), gather g_{t+2}.
    for (int t = 1; t <= Tt - 3; t += 2) {
        update(glA, gbA); // step t
        {
            const int tn = min(t + 1 + D, Tt - 1);
            dma_row(row0 + tn * Cc + lane * 4,
                    &ring[((t + 1) & (D - 1)) * Cc]);
            WAITVM31();
            const int s = (t + 2) & (D - 1);
            glA = lds_gather(&ring[s * Cc + lab]);
            gbA = lds_gather(&ring[s * Cc + BLANK]);
        }
        update(glB, gbB); // step t+1
        {
            const int tn = min(t + 2 + D, Tt - 1);
            dma_row(row0 + tn * Cc + lane * 4,
                    &ring[((t + 2) & (D - 1)) * Cc]);
            WAITVM31();
            const int s = (t + 3) & (D - 1);
            glB = lds_gather(&ring[s * Cc + lab]);
            gbB = lds_gather(&ring[s * Cc + BLANK]);
        }
    }
    // tail: step t = 1023 (glA holds g_1023, gathered in the last A-body)
    update(glA, gbA);

    if (lane == 63) {
        const float m = fmaxf(a128, ao);
        out[b] = -(m + __logf(__expf(a128 - m) + __expf(ao - m)));
    }
}

extern "C" void kernel_launch(void* const* d_in, const int* in_sizes, int n_in,
                              void* d_out, int out_size, void* d_ws,
                              size_t ws_size, hipStream_t stream) {
    const int* y_true = (const int*)d_in[0];     // [512,64] int32
    const float* y_pred = (const float*)d_in[1]; // [512,1024,256] fp32
    float* out = (float*)d_out;                  // [512] fp32

    ctc_fwd_kernel<<<dim3(Bb), dim3(64), 0, stream>>>(y_true, y_pred, out);
}